// Round 3
// baseline (2949.916 us; speedup 1.0000x reference)
//
#include <hip/hip_runtime.h>

#define F 128
#define NB 64            // dst nodes per bucket
#define MAXB 2048        // scan capacity (buckets)

static __device__ __forceinline__ unsigned short f2bf(float f) {
    unsigned u = __float_as_uint(f);
    unsigned r = (u + 0x7FFF + ((u >> 16) & 1)) >> 16;  // RNE
    return (unsigned short)r;
}

// ---------------- GEMM: Sb = bf16(X @ W) ----------------
__global__ __launch_bounds__(256) void gemm_xw_kernel(const float* __restrict__ X,
                                                      const float* __restrict__ W,
                                                      unsigned short* __restrict__ Sb,
                                                      int n_nodes) {
    __shared__ float Wl[F * F];  // 64 KB
    for (int i = threadIdx.x; i < F * F / 4; i += blockDim.x) {
        ((float4*)Wl)[i] = ((const float4*)W)[i];
    }
    __syncthreads();

    const int ROWS = 64;
    int rowBase = blockIdx.x * ROWS;
    int fbase = (threadIdx.x & 31) * 4;
    int rsub = threadIdx.x >> 5;

    for (int r = rsub; r < ROWS; r += 8) {
        int row = rowBase + r;
        if (row >= n_nodes) break;
        const float* xr = X + (size_t)row * F;
        float ax = 0.f, ay = 0.f, az = 0.f, aw = 0.f;
#pragma unroll 8
        for (int k = 0; k < F; ++k) {
            float xv = xr[k];
            float4 wv = *(const float4*)&Wl[k * F + fbase];
            ax += xv * wv.x; ay += xv * wv.y; az += xv * wv.z; aw += xv * wv.w;
        }
        ushort4 res;
        res.x = f2bf(ax); res.y = f2bf(ay); res.z = f2bf(az); res.w = f2bf(aw);
        *(ushort4*)&Sb[(size_t)row * F + fbase] = res;
    }
}

// ---------------- bucket histogram (LDS-aggregated) ----------------
__global__ __launch_bounds__(256) void bhist_kernel(const int* __restrict__ edst,
                                                    int* __restrict__ bcnt,
                                                    int n_edges, int nbuck) {
    __shared__ int h[MAXB];
    for (int i = threadIdx.x; i < nbuck; i += blockDim.x) h[i] = 0;
    __syncthreads();
    for (int e = blockIdx.x * blockDim.x + threadIdx.x; e < n_edges;
         e += gridDim.x * blockDim.x) {
        atomicAdd(&h[edst[e] >> 6], 1);
    }
    __syncthreads();
    for (int i = threadIdx.x; i < nbuck; i += blockDim.x) {
        int v = h[i];
        if (v) __hip_atomic_fetch_add(&bcnt[i], v, __ATOMIC_RELAXED, __HIP_MEMORY_SCOPE_AGENT);
    }
}

// ---------------- single-block exclusive scan over buckets ----------------
__global__ __launch_bounds__(256) void bscan_kernel(const int* __restrict__ bcnt,
                                                    int* __restrict__ bstart,
                                                    int* __restrict__ bcursor, int nbuck) {
    __shared__ int tsum[256];
    int t = threadIdx.x;
    const int EPT = MAXB / 256;  // 8
    int base = t * EPT;
    int v[EPT];
    int s = 0;
#pragma unroll
    for (int i = 0; i < EPT; ++i) {
        int idx = base + i;
        v[i] = (idx < nbuck) ? bcnt[idx] : 0;
        s += v[i];
    }
    tsum[t] = s;
    __syncthreads();
    for (int off = 1; off < 256; off <<= 1) {
        int x = (t >= off) ? tsum[t - off] : 0;
        __syncthreads();
        tsum[t] += x;
        __syncthreads();
    }
    int run = tsum[t] - s;  // exclusive prefix
#pragma unroll
    for (int i = 0; i < EPT; ++i) {
        int idx = base + i;
        if (idx < nbuck) {
            bstart[idx] = run;
            bcursor[idx] = run;
            run += v[i];
        }
    }
    if (t == 255) bstart[nbuck] = run;  // total
}

// ---------------- bucket scatter: ebuf[pos] = {src | dstlow<<20, w} ----------------
__global__ __launch_bounds__(256) void bucket_scatter_kernel(const int* __restrict__ esrc,
                                                             const int* __restrict__ edst,
                                                             const float* __restrict__ ew,
                                                             int* __restrict__ bcursor,
                                                             int2* __restrict__ ebuf, int n_edges) {
    for (int e = blockIdx.x * blockDim.x + threadIdx.x; e < n_edges;
         e += gridDim.x * blockDim.x) {
        int d = edst[e];
        int b = d >> 6;
        int pos = __hip_atomic_fetch_add(&bcursor[b], 1, __ATOMIC_RELAXED, __HIP_MEMORY_SCOPE_AGENT);
        int2 p;
        p.x = esrc[e] | ((d & (NB - 1)) << 20);
        p.y = __float_as_int(ew[e]);
        ebuf[pos] = p;
    }
}

// ---------------- SpMM: one block per bucket, LDS fp32 accumulators ----------------
__global__ __launch_bounds__(512) void spmm_kernel(const unsigned short* __restrict__ Sb,
                                                   const int2* __restrict__ ebuf,
                                                   const int* __restrict__ bstart,
                                                   const float* __restrict__ bias,
                                                   float* __restrict__ out, int n_nodes) {
    __shared__ float acc[NB * F];  // 32 KB
    int t = threadIdx.x;
    int b = blockIdx.x;

    for (int i = t; i < NB * F / 4; i += 512) {
        ((float4*)acc)[i] = float4{0.f, 0.f, 0.f, 0.f};
    }
    __syncthreads();

    int beg = bstart[b], end = bstart[b + 1];
    int w = t >> 6, lane = t & 63;
    int f0 = 2 * lane;

    for (int e = beg + w * 4; e < end; e += 32) {
        if (e + 4 <= end) {
            int2 p0 = ebuf[e], p1 = ebuf[e + 1], p2 = ebuf[e + 2], p3 = ebuf[e + 3];
            unsigned g0 = *(const unsigned*)(Sb + (size_t)(p0.x & 0xFFFFF) * F + f0);
            unsigned g1 = *(const unsigned*)(Sb + (size_t)(p1.x & 0xFFFFF) * F + f0);
            unsigned g2 = *(const unsigned*)(Sb + (size_t)(p2.x & 0xFFFFF) * F + f0);
            unsigned g3 = *(const unsigned*)(Sb + (size_t)(p3.x & 0xFFFFF) * F + f0);

            float w0 = __int_as_float(p0.y); int d0 = (p0.x >> 20) & (NB - 1);
            float w1 = __int_as_float(p1.y); int d1 = (p1.x >> 20) & (NB - 1);
            float w2 = __int_as_float(p2.y); int d2 = (p2.x >> 20) & (NB - 1);
            float w3 = __int_as_float(p3.y); int d3 = (p3.x >> 20) & (NB - 1);

            atomicAdd(&acc[d0 * F + f0],     w0 * __uint_as_float(g0 << 16));
            atomicAdd(&acc[d0 * F + f0 + 1], w0 * __uint_as_float(g0 & 0xFFFF0000u));
            atomicAdd(&acc[d1 * F + f0],     w1 * __uint_as_float(g1 << 16));
            atomicAdd(&acc[d1 * F + f0 + 1], w1 * __uint_as_float(g1 & 0xFFFF0000u));
            atomicAdd(&acc[d2 * F + f0],     w2 * __uint_as_float(g2 << 16));
            atomicAdd(&acc[d2 * F + f0 + 1], w2 * __uint_as_float(g2 & 0xFFFF0000u));
            atomicAdd(&acc[d3 * F + f0],     w3 * __uint_as_float(g3 << 16));
            atomicAdd(&acc[d3 * F + f0 + 1], w3 * __uint_as_float(g3 & 0xFFFF0000u));
        } else {
            for (int j = 0; j < end - e; ++j) {
                int2 p = ebuf[e + j];
                unsigned g = *(const unsigned*)(Sb + (size_t)(p.x & 0xFFFFF) * F + f0);
                float ww = __int_as_float(p.y);
                int dl = (p.x >> 20) & (NB - 1);
                atomicAdd(&acc[dl * F + f0],     ww * __uint_as_float(g << 16));
                atomicAdd(&acc[dl * F + f0 + 1], ww * __uint_as_float(g & 0xFFFF0000u));
            }
        }
    }
    __syncthreads();

    int node_l = t >> 3;
    int fb = (t & 7) * 16;
    int node = b * NB + node_l;
    if (node < n_nodes) {
#pragma unroll
        for (int j = 0; j < 16; j += 4) {
            float4 a = *(float4*)&acc[node_l * F + fb + j];
            float4 bi = *(const float4*)&bias[fb + j];
            a.x += bi.x; a.y += bi.y; a.z += bi.z; a.w += bi.w;
            *(float4*)&out[(size_t)node * F + fb + j] = a;
        }
    }
}

// ---------------- fallback (atomic) path ----------------
__global__ __launch_bounds__(256) void init_out_kernel(float* __restrict__ out,
                                                       const float* __restrict__ bias,
                                                       int n_nodes) {
    int idx = blockIdx.x * blockDim.x + threadIdx.x;
    int total = n_nodes * F;
    if (idx < total) out[idx] = bias[idx & (F - 1)];
}

__global__ __launch_bounds__(256) void scatter_edges_kernel(const unsigned short* __restrict__ Sb,
                                                            const int* __restrict__ esrc,
                                                            const int* __restrict__ edst,
                                                            const float* __restrict__ ew,
                                                            float* __restrict__ out,
                                                            int n_edges) {
    long long idx = (long long)blockIdx.x * blockDim.x + threadIdx.x;
    int e = (int)(idx >> 5);
    if (e >= n_edges) return;
    int fbase = ((int)idx & 31) * 4;
    int s = esrc[e];
    int d = edst[e];
    float w = ew[e];
    ushort4 v = *(const ushort4*)&Sb[(size_t)s * F + fbase];
    float* o = out + (size_t)d * F + fbase;
    __hip_atomic_fetch_add(&o[0], w * __uint_as_float((unsigned)v.x << 16), __ATOMIC_RELAXED, __HIP_MEMORY_SCOPE_AGENT);
    __hip_atomic_fetch_add(&o[1], w * __uint_as_float((unsigned)v.y << 16), __ATOMIC_RELAXED, __HIP_MEMORY_SCOPE_AGENT);
    __hip_atomic_fetch_add(&o[2], w * __uint_as_float((unsigned)v.z << 16), __ATOMIC_RELAXED, __HIP_MEMORY_SCOPE_AGENT);
    __hip_atomic_fetch_add(&o[3], w * __uint_as_float((unsigned)v.w << 16), __ATOMIC_RELAXED, __HIP_MEMORY_SCOPE_AGENT);
}

extern "C" void kernel_launch(void* const* d_in, const int* in_sizes, int n_in,
                              void* d_out, int out_size, void* d_ws, size_t ws_size,
                              hipStream_t stream) {
    const float* x    = (const float*)d_in[0];
    const float* w    = (const float*)d_in[1];
    const float* bias = (const float*)d_in[2];
    const int*   esrc = (const int*)d_in[3];
    const int*   edst = (const int*)d_in[4];
    const float* ew   = (const float*)d_in[5];
    float* out = (float*)d_out;

    int n_nodes = in_sizes[0] / F;
    int n_edges = in_sizes[3];
    int nbuck = (n_nodes + NB - 1) / NB;

    size_t off = 0;
    auto carve = [&](size_t bytes) -> void* {
        void* p = (char*)d_ws + off;
        off += (bytes + 255) & ~(size_t)255;
        return p;
    };
    unsigned short* Sb   = (unsigned short*)carve((size_t)n_nodes * F * sizeof(unsigned short));
    int2*           ebuf = (int2*)carve((size_t)n_edges * sizeof(int2));
    int*            bcnt = (int*)carve((size_t)nbuck * sizeof(int));
    int*            bst  = (int*)carve((size_t)(nbuck + 1) * sizeof(int));
    int*            bcur = (int*)carve((size_t)nbuck * sizeof(int));
    bool ok = (off <= ws_size) && (nbuck <= MAXB) && (n_nodes < (1 << 20));

    // Sb = bf16(X @ W)
    gemm_xw_kernel<<<(n_nodes + 63) / 64, 256, 0, stream>>>(x, w, Sb, n_nodes);

    if (ok) {
        hipMemsetAsync(bcnt, 0, (size_t)nbuck * sizeof(int), stream);
        bhist_kernel<<<1024, 256, 0, stream>>>(edst, bcnt, n_edges, nbuck);
        bscan_kernel<<<1, 256, 0, stream>>>(bcnt, bst, bcur, nbuck);
        bucket_scatter_kernel<<<2048, 256, 0, stream>>>(esrc, edst, ew, bcur, ebuf, n_edges);
        spmm_kernel<<<nbuck, 512, 0, stream>>>(Sb, ebuf, bst, bias, out, n_nodes);
    } else {
        int total = n_nodes * F;
        init_out_kernel<<<(total + 255) / 256, 256, 0, stream>>>(out, bias, n_nodes);
        long long t2 = (long long)n_edges * 32;
        scatter_edges_kernel<<<(int)((t2 + 255) / 256), 256, 0, stream>>>(Sb, esrc, edst, ew, out,
                                                                          n_edges);
    }
}

// Round 4
// 761.775 us; speedup vs baseline: 3.8724x; 3.8724x over previous
//
#include <hip/hip_runtime.h>

#define F 128
#define NB 64            // dst nodes per bucket
#define MAXB 2048        // bucket-scan capacity

static __device__ __forceinline__ unsigned short f2bf(float f) {
    unsigned u = __float_as_uint(f);
    unsigned r = (u + 0x7FFF + ((u >> 16) & 1)) >> 16;  // RNE
    return (unsigned short)r;
}

// ---------------- GEMM: Sb = bf16(X @ W) ----------------
__global__ __launch_bounds__(256) void gemm_xw_kernel(const float* __restrict__ X,
                                                      const float* __restrict__ W,
                                                      unsigned short* __restrict__ Sb,
                                                      int n_nodes) {
    __shared__ float Wl[F * F];  // 64 KB
    for (int i = threadIdx.x; i < F * F / 4; i += blockDim.x) {
        ((float4*)Wl)[i] = ((const float4*)W)[i];
    }
    __syncthreads();

    const int ROWS = 64;
    int rowBase = blockIdx.x * ROWS;
    int fbase = (threadIdx.x & 31) * 4;
    int rsub = threadIdx.x >> 5;

    for (int r = rsub; r < ROWS; r += 8) {
        int row = rowBase + r;
        if (row >= n_nodes) break;
        const float* xr = X + (size_t)row * F;
        float ax = 0.f, ay = 0.f, az = 0.f, aw = 0.f;
#pragma unroll 8
        for (int k = 0; k < F; ++k) {
            float xv = xr[k];
            float4 wv = *(const float4*)&Wl[k * F + fbase];
            ax += xv * wv.x; ay += xv * wv.y; az += xv * wv.z; aw += xv * wv.w;
        }
        ushort4 res;
        res.x = f2bf(ax); res.y = f2bf(ay); res.z = f2bf(az); res.w = f2bf(aw);
        *(ushort4*)&Sb[(size_t)row * F + fbase] = res;
    }
}

// ---------------- bucket histogram (LDS-aggregated) ----------------
__global__ __launch_bounds__(256) void bhist_kernel(const int* __restrict__ edst,
                                                    int* __restrict__ bcnt,
                                                    int n_edges, int nbuck) {
    __shared__ int h[MAXB];
    for (int i = threadIdx.x; i < nbuck; i += blockDim.x) h[i] = 0;
    __syncthreads();
    for (int e = blockIdx.x * blockDim.x + threadIdx.x; e < n_edges;
         e += gridDim.x * blockDim.x) {
        atomicAdd(&h[edst[e] >> 6], 1);
    }
    __syncthreads();
    for (int i = threadIdx.x; i < nbuck; i += blockDim.x) {
        int v = h[i];
        if (v) __hip_atomic_fetch_add(&bcnt[i], v, __ATOMIC_RELAXED, __HIP_MEMORY_SCOPE_AGENT);
    }
}

// ---------------- single-block exclusive scan over buckets ----------------
__global__ __launch_bounds__(256) void bscan_kernel(const int* __restrict__ bcnt,
                                                    int* __restrict__ bstart,
                                                    int* __restrict__ bcursor, int nbuck) {
    __shared__ int tsum[256];
    int t = threadIdx.x;
    const int EPT = MAXB / 256;  // 8
    int base = t * EPT;
    int v[EPT];
    int s = 0;
#pragma unroll
    for (int i = 0; i < EPT; ++i) {
        int idx = base + i;
        v[i] = (idx < nbuck) ? bcnt[idx] : 0;
        s += v[i];
    }
    tsum[t] = s;
    __syncthreads();
    for (int off = 1; off < 256; off <<= 1) {
        int x = (t >= off) ? tsum[t - off] : 0;
        __syncthreads();
        tsum[t] += x;
        __syncthreads();
    }
    int run = tsum[t] - s;  // exclusive prefix
#pragma unroll
    for (int i = 0; i < EPT; ++i) {
        int idx = base + i;
        if (idx < nbuck) {
            bstart[idx] = run;
            bcursor[idx] = run;
            run += v[i];
        }
    }
    if (t == 255) bstart[nbuck] = run;  // total
}

// ---------------- bucket scatter: ebuf[pos] = {src | dstlow<<20, w} ----------------
__global__ __launch_bounds__(256) void bucket_scatter_kernel(const int* __restrict__ esrc,
                                                             const int* __restrict__ edst,
                                                             const float* __restrict__ ew,
                                                             int* __restrict__ bcursor,
                                                             int2* __restrict__ ebuf, int n_edges) {
    for (int e = blockIdx.x * blockDim.x + threadIdx.x; e < n_edges;
         e += gridDim.x * blockDim.x) {
        int d = edst[e];
        int b = d >> 6;
        int pos = __hip_atomic_fetch_add(&bcursor[b], 1, __ATOMIC_RELAXED, __HIP_MEMORY_SCOPE_AGENT);
        int2 p;
        p.x = esrc[e] | ((d & (NB - 1)) << 20);
        p.y = __float_as_int(ew[e]);
        ebuf[pos] = p;
    }
}

// ---------------- per-bucket counting sort -> node-exact CSR ----------------
__global__ __launch_bounds__(256) void local_sort_kernel(const int2* __restrict__ ebuf,
                                                         const int* __restrict__ bstart,
                                                         int2* __restrict__ csr,
                                                         int* __restrict__ rowst,
                                                         int* __restrict__ cnt_out, int n_nodes) {
    __shared__ int lcnt[NB];
    __shared__ int lcur[NB];
    int b = blockIdx.x, t = threadIdx.x;
    int beg = bstart[b], end = bstart[b + 1];

    if (t < NB) lcnt[t] = 0;
    __syncthreads();

    for (int e = beg + t; e < end; e += 256) {
        int dl = (ebuf[e].x >> 20) & (NB - 1);
        atomicAdd(&lcnt[dl], 1);
    }
    __syncthreads();

    if (t < NB) {  // one full wave: shfl inclusive scan over 64 counters
        int v = lcnt[t];
        int inc = v;
#pragma unroll
        for (int off = 1; off < NB; off <<= 1) {
            int up = __shfl_up(inc, off, NB);
            if (t >= off) inc += up;
        }
        int excl = inc - v;
        lcur[t] = excl;
        int node = b * NB + t;
        if (node < n_nodes) {
            rowst[node] = beg + excl;
            cnt_out[node] = v;
        }
    }
    __syncthreads();

    for (int e = beg + t; e < end; e += 256) {
        int2 p = ebuf[e];
        int dl = (p.x >> 20) & (NB - 1);
        int pos = beg + atomicAdd(&lcur[dl], 1);
        int2 q;
        q.x = p.x & 0xFFFFF;
        q.y = p.y;
        csr[pos] = q;
    }
}

// ---------------- gather: one wave per dst node ----------------
__global__ __launch_bounds__(256) void gather_kernel(const unsigned short* __restrict__ Sb,
                                                     const int2* __restrict__ csr,
                                                     const int* __restrict__ rowst,
                                                     const int* __restrict__ cnt,
                                                     const float* __restrict__ bias,
                                                     float* __restrict__ out, int n_nodes) {
    int node = blockIdx.x * 4 + (threadIdx.x >> 6);
    if (node >= n_nodes) return;
    int lane = threadIdx.x & 63;
    int f0 = lane * 2;

    float2 acc = *(const float2*)&bias[f0];
    int beg = rowst[node];
    int num = cnt[node];

    int i = 0;
    for (; i + 8 <= num; i += 8) {
        unsigned g[8];
        float wv[8];
#pragma unroll
        for (int j = 0; j < 8; ++j) {
            int2 p = csr[beg + i + j];
            g[j] = *(const unsigned*)(Sb + (size_t)p.x * F + f0);
            wv[j] = __int_as_float(p.y);
        }
#pragma unroll
        for (int j = 0; j < 8; ++j) {
            acc.x += wv[j] * __uint_as_float(g[j] << 16);
            acc.y += wv[j] * __uint_as_float(g[j] & 0xFFFF0000u);
        }
    }
    for (; i < num; ++i) {
        int2 p = csr[beg + i];
        unsigned g = *(const unsigned*)(Sb + (size_t)p.x * F + f0);
        float w = __int_as_float(p.y);
        acc.x += w * __uint_as_float(g << 16);
        acc.y += w * __uint_as_float(g & 0xFFFF0000u);
    }
    *(float2*)&out[(size_t)node * F + f0] = acc;
}

// ---------------- fallback (atomic) path ----------------
__global__ __launch_bounds__(256) void init_out_kernel(float* __restrict__ out,
                                                       const float* __restrict__ bias,
                                                       int n_nodes) {
    int idx = blockIdx.x * blockDim.x + threadIdx.x;
    int total = n_nodes * F;
    if (idx < total) out[idx] = bias[idx & (F - 1)];
}

__global__ __launch_bounds__(256) void scatter_edges_kernel(const unsigned short* __restrict__ Sb,
                                                            const int* __restrict__ esrc,
                                                            const int* __restrict__ edst,
                                                            const float* __restrict__ ew,
                                                            float* __restrict__ out,
                                                            int n_edges) {
    long long idx = (long long)blockIdx.x * blockDim.x + threadIdx.x;
    int e = (int)(idx >> 5);
    if (e >= n_edges) return;
    int fbase = ((int)idx & 31) * 4;
    int s = esrc[e];
    int d = edst[e];
    float w = ew[e];
    ushort4 v = *(const ushort4*)&Sb[(size_t)s * F + fbase];
    float* o = out + (size_t)d * F + fbase;
    __hip_atomic_fetch_add(&o[0], w * __uint_as_float((unsigned)v.x << 16), __ATOMIC_RELAXED, __HIP_MEMORY_SCOPE_AGENT);
    __hip_atomic_fetch_add(&o[1], w * __uint_as_float((unsigned)v.y << 16), __ATOMIC_RELAXED, __HIP_MEMORY_SCOPE_AGENT);
    __hip_atomic_fetch_add(&o[2], w * __uint_as_float((unsigned)v.z << 16), __ATOMIC_RELAXED, __HIP_MEMORY_SCOPE_AGENT);
    __hip_atomic_fetch_add(&o[3], w * __uint_as_float((unsigned)v.w << 16), __ATOMIC_RELAXED, __HIP_MEMORY_SCOPE_AGENT);
}

extern "C" void kernel_launch(void* const* d_in, const int* in_sizes, int n_in,
                              void* d_out, int out_size, void* d_ws, size_t ws_size,
                              hipStream_t stream) {
    const float* x    = (const float*)d_in[0];
    const float* w    = (const float*)d_in[1];
    const float* bias = (const float*)d_in[2];
    const int*   esrc = (const int*)d_in[3];
    const int*   edst = (const int*)d_in[4];
    const float* ew   = (const float*)d_in[5];
    float* out = (float*)d_out;

    int n_nodes = in_sizes[0] / F;
    int n_edges = in_sizes[3];
    int nbuck = (n_nodes + NB - 1) / NB;

    size_t off = 0;
    auto carve = [&](size_t bytes) -> void* {
        void* p = (char*)d_ws + off;
        off += (bytes + 255) & ~(size_t)255;
        return p;
    };
    unsigned short* Sb   = (unsigned short*)carve((size_t)n_nodes * F * sizeof(unsigned short));
    int2*           ebuf = (int2*)carve((size_t)n_edges * sizeof(int2));
    int2*           csr  = (int2*)carve((size_t)n_edges * sizeof(int2));
    int*            bcnt = (int*)carve((size_t)nbuck * sizeof(int));
    int*            bst  = (int*)carve((size_t)(nbuck + 1) * sizeof(int));
    int*            bcur = (int*)carve((size_t)nbuck * sizeof(int));
    int*            rowst = (int*)carve((size_t)n_nodes * sizeof(int));
    int*            ncnt  = (int*)carve((size_t)n_nodes * sizeof(int));
    bool ok = (off <= ws_size) && (nbuck <= MAXB) && (n_nodes < (1 << 20));

    // Sb = bf16(X @ W)
    gemm_xw_kernel<<<(n_nodes + 63) / 64, 256, 0, stream>>>(x, w, Sb, n_nodes);

    if (ok) {
        hipMemsetAsync(bcnt, 0, (size_t)nbuck * sizeof(int), stream);
        bhist_kernel<<<512, 256, 0, stream>>>(edst, bcnt, n_edges, nbuck);
        bscan_kernel<<<1, 256, 0, stream>>>(bcnt, bst, bcur, nbuck);
        bucket_scatter_kernel<<<2048, 256, 0, stream>>>(esrc, edst, ew, bcur, ebuf, n_edges);
        local_sort_kernel<<<nbuck, 256, 0, stream>>>(ebuf, bst, csr, rowst, ncnt, n_nodes);
        gather_kernel<<<(n_nodes + 3) / 4, 256, 0, stream>>>(Sb, csr, rowst, ncnt, bias, out,
                                                             n_nodes);
    } else {
        int total = n_nodes * F;
        init_out_kernel<<<(total + 255) / 256, 256, 0, stream>>>(out, bias, n_nodes);
        long long t2 = (long long)n_edges * 32;
        scatter_edges_kernel<<<(int)((t2 + 255) / 256), 256, 0, stream>>>(Sb, esrc, edst, ew, out,
                                                                          n_edges);
    }
}

// Round 5
// 380.360 us; speedup vs baseline: 7.7556x; 2.0028x over previous
//
#include <hip/hip_runtime.h>

#define F 128
#define NB 64            // dst nodes per bucket
#define MAXB 2048        // max buckets
#define NCHUNK 256       // edge chunks for deterministic partition

static __device__ __forceinline__ unsigned short f2bf(float f) {
    unsigned u = __float_as_uint(f);
    unsigned r = (u + 0x7FFF + ((u >> 16) & 1)) >> 16;  // RNE
    return (unsigned short)r;
}

// ---------------- GEMM: Sb = bf16(X @ W) ----------------
__global__ __launch_bounds__(256) void gemm_xw_kernel(const float* __restrict__ X,
                                                      const float* __restrict__ W,
                                                      unsigned short* __restrict__ Sb,
                                                      int n_nodes) {
    __shared__ float Wl[F * F];  // 64 KB
    for (int i = threadIdx.x; i < F * F / 4; i += blockDim.x) {
        ((float4*)Wl)[i] = ((const float4*)W)[i];
    }
    __syncthreads();

    const int ROWS = 64;
    int rowBase = blockIdx.x * ROWS;
    int fbase = (threadIdx.x & 31) * 4;
    int rsub = threadIdx.x >> 5;

    for (int r = rsub; r < ROWS; r += 8) {
        int row = rowBase + r;
        if (row >= n_nodes) break;
        const float* xr = X + (size_t)row * F;
        float ax = 0.f, ay = 0.f, az = 0.f, aw = 0.f;
#pragma unroll 8
        for (int k = 0; k < F; ++k) {
            float xv = xr[k];
            float4 wv = *(const float4*)&Wl[k * F + fbase];
            ax += xv * wv.x; ay += xv * wv.y; az += xv * wv.z; aw += xv * wv.w;
        }
        ushort4 res;
        res.x = f2bf(ax); res.y = f2bf(ay); res.z = f2bf(az); res.w = f2bf(aw);
        *(ushort4*)&Sb[(size_t)row * F + fbase] = res;
    }
}

// ---------------- phase A: per-chunk bucket histogram ----------------
__global__ __launch_bounds__(256) void chunk_hist_kernel(const int* __restrict__ edst,
                                                         int* __restrict__ counts,
                                                         int* __restrict__ bcnt,
                                                         int n_edges, int nbuck, int epc) {
    __shared__ int h[MAXB];
    int c = blockIdx.x, t = threadIdx.x;
    for (int i = t; i < nbuck; i += 256) h[i] = 0;
    __syncthreads();
    int beg = c * epc, end = min(n_edges, beg + epc);
    for (int e = beg + t; e < end; e += 256) {
        atomicAdd(&h[edst[e] >> 6], 1);
    }
    __syncthreads();
    for (int i = t; i < nbuck; i += 256) {
        int v = h[i];
        counts[(size_t)c * nbuck + i] = v;
        if (v) __hip_atomic_fetch_add(&bcnt[i], v, __ATOMIC_RELAXED, __HIP_MEMORY_SCOPE_AGENT);
    }
}

// ---------------- exclusive scan over bucket totals ----------------
__global__ __launch_bounds__(256) void bscan_kernel(const int* __restrict__ bcnt,
                                                    int* __restrict__ bstart, int nbuck) {
    __shared__ int tsum[256];
    int t = threadIdx.x;
    const int EPT = MAXB / 256;  // 8
    int base = t * EPT;
    int v[EPT];
    int s = 0;
#pragma unroll
    for (int i = 0; i < EPT; ++i) {
        int idx = base + i;
        v[i] = (idx < nbuck) ? bcnt[idx] : 0;
        s += v[i];
    }
    tsum[t] = s;
    __syncthreads();
    for (int off = 1; off < 256; off <<= 1) {
        int x = (t >= off) ? tsum[t - off] : 0;
        __syncthreads();
        tsum[t] += x;
        __syncthreads();
    }
    int run = tsum[t] - s;  // exclusive prefix
#pragma unroll
    for (int i = 0; i < EPT; ++i) {
        int idx = base + i;
        if (idx < nbuck) {
            bstart[idx] = run;
            run += v[i];
        }
    }
    if (t == 255) bstart[nbuck] = run;
}

// ---------------- phase B: per-bucket scan over chunks -> exact offsets ----------------
__global__ __launch_bounds__(64) void chunk_offs_kernel(const int* __restrict__ counts,
                                                        const int* __restrict__ bstart,
                                                        int* __restrict__ offs, int nbuck) {
    int b = blockIdx.x * 64 + threadIdx.x;
    if (b >= nbuck) return;
    int run = bstart[b];
    for (int c = 0; c < NCHUNK; ++c) {
        int v = counts[(size_t)c * nbuck + b];
        offs[(size_t)c * nbuck + b] = run;
        run += v;
    }
}

// ---------------- phase C: scatter to exact slots, LDS cursors only ----------------
__global__ __launch_bounds__(256) void chunk_scatter_kernel(const int* __restrict__ esrc,
                                                            const int* __restrict__ edst,
                                                            const float* __restrict__ ew,
                                                            const int* __restrict__ offs,
                                                            int2* __restrict__ ebuf,
                                                            int n_edges, int nbuck, int epc) {
    __shared__ int lcur[MAXB];
    int c = blockIdx.x, t = threadIdx.x;
    for (int i = t; i < nbuck; i += 256) lcur[i] = offs[(size_t)c * nbuck + i];
    __syncthreads();
    int beg = c * epc, end = min(n_edges, beg + epc);
    for (int e = beg + t; e < end; e += 256) {
        int d = edst[e];
        int pos = atomicAdd(&lcur[d >> 6], 1);
        int2 p;
        p.x = esrc[e] | ((d & (NB - 1)) << 20);
        p.y = __float_as_int(ew[e]);
        ebuf[pos] = p;
    }
}

// ---------------- per-bucket counting sort -> node-exact CSR ----------------
__global__ __launch_bounds__(256) void local_sort_kernel(const int2* __restrict__ ebuf,
                                                         const int* __restrict__ bstart,
                                                         int2* __restrict__ csr,
                                                         int* __restrict__ rowst,
                                                         int* __restrict__ cnt_out, int n_nodes) {
    __shared__ int lcnt[NB];
    __shared__ int lcur[NB];
    int b = blockIdx.x, t = threadIdx.x;
    int beg = bstart[b], end = bstart[b + 1];

    if (t < NB) lcnt[t] = 0;
    __syncthreads();

    for (int e = beg + t; e < end; e += 256) {
        int dl = (ebuf[e].x >> 20) & (NB - 1);
        atomicAdd(&lcnt[dl], 1);
    }
    __syncthreads();

    if (t < NB) {  // one wave: shfl inclusive scan over 64 counters
        int v = lcnt[t];
        int inc = v;
#pragma unroll
        for (int off = 1; off < NB; off <<= 1) {
            int up = __shfl_up(inc, off, NB);
            if (t >= off) inc += up;
        }
        int excl = inc - v;
        lcur[t] = excl;
        int node = b * NB + t;
        if (node < n_nodes) {
            rowst[node] = beg + excl;
            cnt_out[node] = v;
        }
    }
    __syncthreads();

    for (int e = beg + t; e < end; e += 256) {
        int2 p = ebuf[e];
        int dl = (p.x >> 20) & (NB - 1);
        int pos = beg + atomicAdd(&lcur[dl], 1);
        int2 q;
        q.x = p.x & 0xFFFFF;
        q.y = p.y;
        csr[pos] = q;
    }
}

// ---------------- gather: one wave per dst node ----------------
__global__ __launch_bounds__(256) void gather_kernel(const unsigned short* __restrict__ Sb,
                                                     const int2* __restrict__ csr,
                                                     const int* __restrict__ rowst,
                                                     const int* __restrict__ cnt,
                                                     const float* __restrict__ bias,
                                                     float* __restrict__ out, int n_nodes) {
    int node = blockIdx.x * 4 + (threadIdx.x >> 6);
    if (node >= n_nodes) return;
    int lane = threadIdx.x & 63;
    int f0 = lane * 2;

    float2 acc = *(const float2*)&bias[f0];
    int beg = rowst[node];
    int num = cnt[node];

    int i = 0;
    for (; i + 8 <= num; i += 8) {
        unsigned g[8];
        float wv[8];
#pragma unroll
        for (int j = 0; j < 8; ++j) {
            int2 p = csr[beg + i + j];
            g[j] = *(const unsigned*)(Sb + (size_t)p.x * F + f0);
            wv[j] = __int_as_float(p.y);
        }
#pragma unroll
        for (int j = 0; j < 8; ++j) {
            acc.x += wv[j] * __uint_as_float(g[j] << 16);
            acc.y += wv[j] * __uint_as_float(g[j] & 0xFFFF0000u);
        }
    }
    for (; i < num; ++i) {
        int2 p = csr[beg + i];
        unsigned g = *(const unsigned*)(Sb + (size_t)p.x * F + f0);
        float w = __int_as_float(p.y);
        acc.x += w * __uint_as_float(g << 16);
        acc.y += w * __uint_as_float(g & 0xFFFF0000u);
    }
    *(float2*)&out[(size_t)node * F + f0] = acc;
}

// ---------------- fallback (atomic) path ----------------
__global__ __launch_bounds__(256) void init_out_kernel(float* __restrict__ out,
                                                       const float* __restrict__ bias,
                                                       int n_nodes) {
    int idx = blockIdx.x * blockDim.x + threadIdx.x;
    int total = n_nodes * F;
    if (idx < total) out[idx] = bias[idx & (F - 1)];
}

__global__ __launch_bounds__(256) void scatter_edges_kernel(const unsigned short* __restrict__ Sb,
                                                            const int* __restrict__ esrc,
                                                            const int* __restrict__ edst,
                                                            const float* __restrict__ ew,
                                                            float* __restrict__ out,
                                                            int n_edges) {
    long long idx = (long long)blockIdx.x * blockDim.x + threadIdx.x;
    int e = (int)(idx >> 5);
    if (e >= n_edges) return;
    int fbase = ((int)idx & 31) * 4;
    int s = esrc[e];
    int d = edst[e];
    float w = ew[e];
    ushort4 v = *(const ushort4*)&Sb[(size_t)s * F + fbase];
    float* o = out + (size_t)d * F + fbase;
    __hip_atomic_fetch_add(&o[0], w * __uint_as_float((unsigned)v.x << 16), __ATOMIC_RELAXED, __HIP_MEMORY_SCOPE_AGENT);
    __hip_atomic_fetch_add(&o[1], w * __uint_as_float((unsigned)v.y << 16), __ATOMIC_RELAXED, __HIP_MEMORY_SCOPE_AGENT);
    __hip_atomic_fetch_add(&o[2], w * __uint_as_float((unsigned)v.z << 16), __ATOMIC_RELAXED, __HIP_MEMORY_SCOPE_AGENT);
    __hip_atomic_fetch_add(&o[3], w * __uint_as_float((unsigned)v.w << 16), __ATOMIC_RELAXED, __HIP_MEMORY_SCOPE_AGENT);
}

extern "C" void kernel_launch(void* const* d_in, const int* in_sizes, int n_in,
                              void* d_out, int out_size, void* d_ws, size_t ws_size,
                              hipStream_t stream) {
    const float* x    = (const float*)d_in[0];
    const float* w    = (const float*)d_in[1];
    const float* bias = (const float*)d_in[2];
    const int*   esrc = (const int*)d_in[3];
    const int*   edst = (const int*)d_in[4];
    const float* ew   = (const float*)d_in[5];
    float* out = (float*)d_out;

    int n_nodes = in_sizes[0] / F;
    int n_edges = in_sizes[3];
    int nbuck = (n_nodes + NB - 1) / NB;
    int epc = (n_edges + NCHUNK - 1) / NCHUNK;

    size_t off = 0;
    auto carve = [&](size_t bytes) -> void* {
        void* p = (char*)d_ws + off;
        off += (bytes + 255) & ~(size_t)255;
        return p;
    };
    unsigned short* Sb    = (unsigned short*)carve((size_t)n_nodes * F * sizeof(unsigned short));
    int2*           ebuf  = (int2*)carve((size_t)n_edges * sizeof(int2));
    int2*           csr   = (int2*)carve((size_t)n_edges * sizeof(int2));
    int*            bcnt  = (int*)carve((size_t)nbuck * sizeof(int));
    int*            bst   = (int*)carve((size_t)(nbuck + 1) * sizeof(int));
    int*            rowst = (int*)carve((size_t)n_nodes * sizeof(int));
    int*            ncnt  = (int*)carve((size_t)n_nodes * sizeof(int));
    int*            counts = (int*)carve((size_t)NCHUNK * nbuck * sizeof(int));
    int*            offs   = (int*)carve((size_t)NCHUNK * nbuck * sizeof(int));
    bool ok = (off <= ws_size) && (nbuck <= MAXB) && (n_nodes < (1 << 20));

    // Sb = bf16(X @ W)
    gemm_xw_kernel<<<(n_nodes + 63) / 64, 256, 0, stream>>>(x, w, Sb, n_nodes);

    if (ok) {
        hipMemsetAsync(bcnt, 0, (size_t)nbuck * sizeof(int), stream);
        chunk_hist_kernel<<<NCHUNK, 256, 0, stream>>>(edst, counts, bcnt, n_edges, nbuck, epc);
        bscan_kernel<<<1, 256, 0, stream>>>(bcnt, bst, nbuck);
        chunk_offs_kernel<<<(nbuck + 63) / 64, 64, 0, stream>>>(counts, bst, offs, nbuck);
        chunk_scatter_kernel<<<NCHUNK, 256, 0, stream>>>(esrc, edst, ew, offs, ebuf,
                                                         n_edges, nbuck, epc);
        local_sort_kernel<<<nbuck, 256, 0, stream>>>(ebuf, bst, csr, rowst, ncnt, n_nodes);
        gather_kernel<<<(n_nodes + 3) / 4, 256, 0, stream>>>(Sb, csr, rowst, ncnt, bias, out,
                                                             n_nodes);
    } else {
        int total = n_nodes * F;
        init_out_kernel<<<(total + 255) / 256, 256, 0, stream>>>(out, bias, n_nodes);
        long long t2 = (long long)n_edges * 32;
        scatter_edges_kernel<<<(int)((t2 + 255) / 256), 256, 0, stream>>>(Sb, esrc, edst, ew, out,
                                                                          n_edges);
    }
}

// Round 6
// 252.079 us; speedup vs baseline: 11.7023x; 1.5089x over previous
//
#include <hip/hip_runtime.h>

#define F 128
#define NB 64            // dst nodes per bucket
#define MAXB 2048        // max buckets
#define NCHUNK 256       // edge chunks for deterministic partition

typedef __bf16 bf16x8 __attribute__((ext_vector_type(8)));
typedef unsigned short u16x8 __attribute__((ext_vector_type(8)));
typedef float f32x4 __attribute__((ext_vector_type(4)));

static __device__ __forceinline__ unsigned short f2bf(float f) {
    unsigned u = __float_as_uint(f);
    unsigned r = (u + 0x7FFF + ((u >> 16) & 1)) >> 16;  // RNE
    return (unsigned short)r;
}

// ---------------- MFMA GEMM: Sb = bf16(X @ W) ----------------
// Block: 64 rows; 4 waves x 16 rows. W^T staged bf16 in LDS, XOR-swizzled.
__global__ __launch_bounds__(256) void gemm_mfma_kernel(const float* __restrict__ X,
                                                        const float* __restrict__ W,
                                                        unsigned short* __restrict__ Sb,
                                                        int n_nodes) {
    __shared__ unsigned short WT[F * F];  // 32 KB; element (k,f) at byte f*256 + (k*2 ^ ((f&7)<<4))
    int t = threadIdx.x;
    {
        int f = t >> 1, half = t & 1;
#pragma unroll
        for (int j = 0; j < 8; ++j) {
            int k0 = half * 64 + j * 8;
            u16x8 pk;
#pragma unroll
            for (int i = 0; i < 8; ++i) pk[i] = f2bf(W[(size_t)(k0 + i) * F + f]);
            int byte = f * 256 + ((k0 * 2) ^ ((f & 7) << 4));
            *(u16x8*)((char*)WT + byte) = pk;
        }
    }
    __syncthreads();

    int w = t >> 6, l = t & 63;
    int lr = l & 15, lg = l >> 4;
    int rowBase = blockIdx.x * 64 + w * 16;

    f32x4 acc[8] = {};
    int a_row = rowBase + lr;
    if (a_row >= n_nodes) a_row = n_nodes - 1;  // clamp; stores are guarded
    const float* arow = X + (size_t)a_row * F + lg * 8;

#pragma unroll
    for (int kt = 0; kt < 4; ++kt) {
        const float* ap = arow + kt * 32;
        float4 x0 = *(const float4*)ap;
        float4 x1 = *(const float4*)(ap + 4);
        u16x8 au;
        au[0] = f2bf(x0.x); au[1] = f2bf(x0.y); au[2] = f2bf(x0.z); au[3] = f2bf(x0.w);
        au[4] = f2bf(x1.x); au[5] = f2bf(x1.y); au[6] = f2bf(x1.z); au[7] = f2bf(x1.w);
        bf16x8 a = __builtin_bit_cast(bf16x8, au);
#pragma unroll
        for (int ct = 0; ct < 8; ++ct) {
            int f = ct * 16 + lr;
            int byte = f * 256 + (((kt * 32 + lg * 8) * 2) ^ ((f & 7) << 4));
            bf16x8 b = *(bf16x8*)((char*)WT + byte);
            acc[ct] = __builtin_amdgcn_mfma_f32_16x16x32_bf16(a, b, acc[ct], 0, 0, 0);
        }
    }

#pragma unroll
    for (int ct = 0; ct < 8; ++ct) {
        int col = ct * 16 + lr;
#pragma unroll
        for (int j = 0; j < 4; ++j) {
            int row = rowBase + lg * 4 + j;
            if (row < n_nodes) Sb[(size_t)row * F + col] = f2bf(acc[ct][j]);
        }
    }
}

// ---------------- phase A: per-chunk bucket histogram ----------------
__global__ __launch_bounds__(256) void chunk_hist_kernel(const int* __restrict__ edst,
                                                         int* __restrict__ counts,
                                                         int* __restrict__ bcnt,
                                                         int n_edges, int nbuck, int epc) {
    __shared__ int h[MAXB];
    int c = blockIdx.x, t = threadIdx.x;
    for (int i = t; i < nbuck; i += 256) h[i] = 0;
    __syncthreads();
    int beg = c * epc, end = min(n_edges, beg + epc);
    for (int e = beg + t; e < end; e += 256) {
        atomicAdd(&h[edst[e] >> 6], 1);
    }
    __syncthreads();
    for (int i = t; i < nbuck; i += 256) {
        int v = h[i];
        counts[(size_t)c * nbuck + i] = v;
        if (v) __hip_atomic_fetch_add(&bcnt[i], v, __ATOMIC_RELAXED, __HIP_MEMORY_SCOPE_AGENT);
    }
}

// ---------------- exclusive scan over bucket totals ----------------
__global__ __launch_bounds__(256) void bscan_kernel(const int* __restrict__ bcnt,
                                                    int* __restrict__ bstart, int nbuck) {
    __shared__ int tsum[256];
    int t = threadIdx.x;
    const int EPT = MAXB / 256;  // 8
    int base = t * EPT;
    int v[EPT];
    int s = 0;
#pragma unroll
    for (int i = 0; i < EPT; ++i) {
        int idx = base + i;
        v[i] = (idx < nbuck) ? bcnt[idx] : 0;
        s += v[i];
    }
    tsum[t] = s;
    __syncthreads();
    for (int off = 1; off < 256; off <<= 1) {
        int x = (t >= off) ? tsum[t - off] : 0;
        __syncthreads();
        tsum[t] += x;
        __syncthreads();
    }
    int run = tsum[t] - s;  // exclusive prefix
#pragma unroll
    for (int i = 0; i < EPT; ++i) {
        int idx = base + i;
        if (idx < nbuck) {
            bstart[idx] = run;
            run += v[i];
        }
    }
    if (t == 255) bstart[nbuck] = run;
}

// ---------------- phase B: per-bucket scan over chunks -> exact offsets ----------------
__global__ __launch_bounds__(64) void chunk_offs_kernel(const int* __restrict__ counts,
                                                        const int* __restrict__ bstart,
                                                        int* __restrict__ offs, int nbuck) {
    int b = blockIdx.x * 64 + threadIdx.x;
    if (b >= nbuck) return;
    int run = bstart[b];
    for (int c = 0; c < NCHUNK; ++c) {
        int v = counts[(size_t)c * nbuck + b];
        offs[(size_t)c * nbuck + b] = run;
        run += v;
    }
}

// ---------------- phase C: scatter to exact slots, LDS cursors only ----------------
__global__ __launch_bounds__(256) void chunk_scatter_kernel(const int* __restrict__ esrc,
                                                            const int* __restrict__ edst,
                                                            const float* __restrict__ ew,
                                                            const int* __restrict__ offs,
                                                            int2* __restrict__ ebuf,
                                                            int n_edges, int nbuck, int epc) {
    __shared__ int lcur[MAXB];
    int c = blockIdx.x, t = threadIdx.x;
    for (int i = t; i < nbuck; i += 256) lcur[i] = offs[(size_t)c * nbuck + i];
    __syncthreads();
    int beg = c * epc, end = min(n_edges, beg + epc);
    for (int e = beg + t; e < end; e += 256) {
        int d = edst[e];
        int pos = atomicAdd(&lcur[d >> 6], 1);
        int2 p;
        p.x = esrc[e] | ((d & (NB - 1)) << 20);
        p.y = __float_as_int(ew[e]);
        ebuf[pos] = p;
    }
}

// ---------------- per-bucket counting sort -> node-exact CSR ----------------
__global__ __launch_bounds__(256) void local_sort_kernel(const int2* __restrict__ ebuf,
                                                         const int* __restrict__ bstart,
                                                         int2* __restrict__ csr,
                                                         int* __restrict__ rowst,
                                                         int* __restrict__ cnt_out, int n_nodes) {
    __shared__ int lcnt[NB];
    __shared__ int lcur[NB];
    int b = blockIdx.x, t = threadIdx.x;
    int beg = bstart[b], end = bstart[b + 1];

    if (t < NB) lcnt[t] = 0;
    __syncthreads();

    for (int e = beg + t; e < end; e += 256) {
        int dl = (ebuf[e].x >> 20) & (NB - 1);
        atomicAdd(&lcnt[dl], 1);
    }
    __syncthreads();

    if (t < NB) {  // one wave: shfl inclusive scan over 64 counters
        int v = lcnt[t];
        int inc = v;
#pragma unroll
        for (int off = 1; off < NB; off <<= 1) {
            int up = __shfl_up(inc, off, NB);
            if (t >= off) inc += up;
        }
        int excl = inc - v;
        lcur[t] = excl;
        int node = b * NB + t;
        if (node < n_nodes) {
            rowst[node] = beg + excl;
            cnt_out[node] = v;
        }
    }
    __syncthreads();

    for (int e = beg + t; e < end; e += 256) {
        int2 p = ebuf[e];
        int dl = (p.x >> 20) & (NB - 1);
        int pos = beg + atomicAdd(&lcur[dl], 1);
        int2 q;
        q.x = p.x & 0xFFFFF;
        q.y = p.y;
        csr[pos] = q;
    }
}

// ---------------- gather: one wave per dst node ----------------
__global__ __launch_bounds__(256) void gather_kernel(const unsigned short* __restrict__ Sb,
                                                     const int2* __restrict__ csr,
                                                     const int* __restrict__ rowst,
                                                     const int* __restrict__ cnt,
                                                     const float* __restrict__ bias,
                                                     float* __restrict__ out, int n_nodes) {
    int node = blockIdx.x * 4 + (threadIdx.x >> 6);
    if (node >= n_nodes) return;
    int lane = threadIdx.x & 63;
    int f0 = lane * 2;

    float2 acc = *(const float2*)&bias[f0];
    int beg = rowst[node];
    int num = cnt[node];

    int i = 0;
    for (; i + 8 <= num; i += 8) {
        unsigned g[8];
        float wv[8];
#pragma unroll
        for (int j = 0; j < 8; ++j) {
            int2 p = csr[beg + i + j];
            g[j] = *(const unsigned*)(Sb + (size_t)p.x * F + f0);
            wv[j] = __int_as_float(p.y);
        }
#pragma unroll
        for (int j = 0; j < 8; ++j) {
            acc.x += wv[j] * __uint_as_float(g[j] << 16);
            acc.y += wv[j] * __uint_as_float(g[j] & 0xFFFF0000u);
        }
    }
    for (; i < num; ++i) {
        int2 p = csr[beg + i];
        unsigned g = *(const unsigned*)(Sb + (size_t)p.x * F + f0);
        float w = __int_as_float(p.y);
        acc.x += w * __uint_as_float(g << 16);
        acc.y += w * __uint_as_float(g & 0xFFFF0000u);
    }
    *(float2*)&out[(size_t)node * F + f0] = acc;
}

// ---------------- fallback (atomic) path ----------------
__global__ __launch_bounds__(256) void init_out_kernel(float* __restrict__ out,
                                                       const float* __restrict__ bias,
                                                       int n_nodes) {
    int idx = blockIdx.x * blockDim.x + threadIdx.x;
    int total = n_nodes * F;
    if (idx < total) out[idx] = bias[idx & (F - 1)];
}

__global__ __launch_bounds__(256) void scatter_edges_kernel(const unsigned short* __restrict__ Sb,
                                                            const int* __restrict__ esrc,
                                                            const int* __restrict__ edst,
                                                            const float* __restrict__ ew,
                                                            float* __restrict__ out,
                                                            int n_edges) {
    long long idx = (long long)blockIdx.x * blockDim.x + threadIdx.x;
    int e = (int)(idx >> 5);
    if (e >= n_edges) return;
    int fbase = ((int)idx & 31) * 4;
    int s = esrc[e];
    int d = edst[e];
    float w = ew[e];
    ushort4 v = *(const ushort4*)&Sb[(size_t)s * F + fbase];
    float* o = out + (size_t)d * F + fbase;
    __hip_atomic_fetch_add(&o[0], w * __uint_as_float((unsigned)v.x << 16), __ATOMIC_RELAXED, __HIP_MEMORY_SCOPE_AGENT);
    __hip_atomic_fetch_add(&o[1], w * __uint_as_float((unsigned)v.y << 16), __ATOMIC_RELAXED, __HIP_MEMORY_SCOPE_AGENT);
    __hip_atomic_fetch_add(&o[2], w * __uint_as_float((unsigned)v.z << 16), __ATOMIC_RELAXED, __HIP_MEMORY_SCOPE_AGENT);
    __hip_atomic_fetch_add(&o[3], w * __uint_as_float((unsigned)v.w << 16), __ATOMIC_RELAXED, __HIP_MEMORY_SCOPE_AGENT);
}

extern "C" void kernel_launch(void* const* d_in, const int* in_sizes, int n_in,
                              void* d_out, int out_size, void* d_ws, size_t ws_size,
                              hipStream_t stream) {
    const float* x    = (const float*)d_in[0];
    const float* w    = (const float*)d_in[1];
    const float* bias = (const float*)d_in[2];
    const int*   esrc = (const int*)d_in[3];
    const int*   edst = (const int*)d_in[4];
    const float* ew   = (const float*)d_in[5];
    float* out = (float*)d_out;

    int n_nodes = in_sizes[0] / F;
    int n_edges = in_sizes[3];
    int nbuck = (n_nodes + NB - 1) / NB;
    int epc = (n_edges + NCHUNK - 1) / NCHUNK;

    size_t off = 0;
    auto carve = [&](size_t bytes) -> void* {
        void* p = (char*)d_ws + off;
        off += (bytes + 255) & ~(size_t)255;
        return p;
    };
    unsigned short* Sb    = (unsigned short*)carve((size_t)n_nodes * F * sizeof(unsigned short));
    int2*           ebuf  = (int2*)carve((size_t)n_edges * sizeof(int2));
    int2*           csr   = (int2*)carve((size_t)n_edges * sizeof(int2));
    int*            bcnt  = (int*)carve((size_t)nbuck * sizeof(int));
    int*            bst   = (int*)carve((size_t)(nbuck + 1) * sizeof(int));
    int*            rowst = (int*)carve((size_t)n_nodes * sizeof(int));
    int*            ncnt  = (int*)carve((size_t)n_nodes * sizeof(int));
    int*            counts = (int*)carve((size_t)NCHUNK * nbuck * sizeof(int));
    int*            offs   = (int*)carve((size_t)NCHUNK * nbuck * sizeof(int));
    bool ok = (off <= ws_size) && (nbuck <= MAXB) && (n_nodes < (1 << 20));

    // Sb = bf16(X @ W) via MFMA
    gemm_mfma_kernel<<<(n_nodes + 63) / 64, 256, 0, stream>>>(x, w, Sb, n_nodes);

    if (ok) {
        hipMemsetAsync(bcnt, 0, (size_t)nbuck * sizeof(int), stream);
        chunk_hist_kernel<<<NCHUNK, 256, 0, stream>>>(edst, counts, bcnt, n_edges, nbuck, epc);
        bscan_kernel<<<1, 256, 0, stream>>>(bcnt, bst, nbuck);
        chunk_offs_kernel<<<(nbuck + 63) / 64, 64, 0, stream>>>(counts, bst, offs, nbuck);
        chunk_scatter_kernel<<<NCHUNK, 256, 0, stream>>>(esrc, edst, ew, offs, ebuf,
                                                         n_edges, nbuck, epc);
        local_sort_kernel<<<nbuck, 256, 0, stream>>>(ebuf, bst, csr, rowst, ncnt, n_nodes);
        gather_kernel<<<(n_nodes + 3) / 4, 256, 0, stream>>>(Sb, csr, rowst, ncnt, bias, out,
                                                             n_nodes);
    } else {
        int total = n_nodes * F;
        init_out_kernel<<<(total + 255) / 256, 256, 0, stream>>>(out, bias, n_nodes);
        long long t2 = (long long)n_edges * 32;
        scatter_edges_kernel<<<(int)((t2 + 255) / 256), 256, 0, stream>>>(Sb, esrc, edst, ew, out,
                                                                          n_edges);
    }
}